// Round 4
// baseline (1993.389 us; speedup 1.0000x reference)
//
#include <hip/hip_runtime.h>
#include <hip/hip_bf16.h>
#include <hip/hip_fp16.h>
#include <math.h>

// Problem constants (B,T,D,E,H,K fixed by the reference)
#define DD   1024
#define EE   8
#define HH   512
#define NTOK 16384        // B*T
#define NG   (EE*2)       // (expert, slot) groups

typedef __attribute__((ext_vector_type(8))) short short8;   // 8 bf16 (4 VGPRs)
typedef __attribute__((ext_vector_type(4))) float floatx4;  // MFMA C/D frag

__device__ __forceinline__ ushort f2bfu(float f) {
    __hip_bfloat16 h = __float2bfloat16(f);   // RNE
    return *reinterpret_cast<ushort*>(&h);
}
__device__ __forceinline__ float bfu2f(ushort u) {
    union { unsigned u; float f; } cv; cv.u = ((unsigned)u) << 16; return cv.f;
}
// load 8 consecutive floats, round to bf16, pack as MFMA half-fragment
__device__ __forceinline__ short8 cvt8(const float* __restrict__ p) {
    const float4 a = *(const float4*)p;
    const float4 b = *(const float4*)(p + 4);
    union { short8 s; ushort h[8]; } r;
    r.h[0] = f2bfu(a.x); r.h[1] = f2bfu(a.y); r.h[2] = f2bfu(a.z); r.h[3] = f2bfu(a.w);
    r.h[4] = f2bfu(b.x); r.h[5] = f2bfu(b.y); r.h[6] = f2bfu(b.z); r.h[7] = f2bfu(b.w);
    return r.s;
}

// ---------------------------------------------------------------------------
// Kernel 0: zero the 16 group counters (capture-safe, no hipMemsetAsync)
// ---------------------------------------------------------------------------
__global__ void zero_k(int* __restrict__ cnt) {
    if (blockIdx.x == 0 && threadIdx.x < NG) cnt[threadIdx.x] = 0;
}

// ---------------------------------------------------------------------------
// Kernel 1: router (all fp32 math, matching the np reference's precision).
// One wave per token: logits/noise-logits dots, noisy top-2, 2-way softmax.
// Appends packed (tok | gate_f16<<16) to group g = expert*2 + slot.
// ---------------------------------------------------------------------------
__global__ __launch_bounds__(256) void router_k(
    const float* __restrict__ x, const float* __restrict__ Wr, const float* __restrict__ br,
    const float* __restrict__ Wn, const float* __restrict__ bn, const float* __restrict__ noise,
    int* __restrict__ cnt, unsigned* __restrict__ entries)
{
    const int wave = threadIdx.x >> 6;
    const int lane = threadIdx.x & 63;
    const int t = blockIdx.x * 4 + wave;

    float accr[EE], accn[EE];
#pragma unroll
    for (int e = 0; e < EE; ++e) { accr[e] = 0.f; accn[e] = 0.f; }

    const float* xr = x + (size_t)t * DD;
#pragma unroll 4
    for (int it = 0; it < DD / 64; ++it) {
        const int d = it * 64 + lane;
        const float xv = xr[d];
        float wr[8], wn[8];
        *(float4*)&wr[0] = *(const float4*)(Wr + (size_t)d * EE);
        *(float4*)&wr[4] = *(const float4*)(Wr + (size_t)d * EE + 4);
        *(float4*)&wn[0] = *(const float4*)(Wn + (size_t)d * EE);
        *(float4*)&wn[4] = *(const float4*)(Wn + (size_t)d * EE + 4);
#pragma unroll
        for (int e = 0; e < EE; ++e) {
            accr[e] = fmaf(xv, wr[e], accr[e]);
            accn[e] = fmaf(xv, wn[e], accn[e]);
        }
    }
#pragma unroll
    for (int off = 32; off > 0; off >>= 1) {
#pragma unroll
        for (int e = 0; e < EE; ++e) {
            accr[e] += __shfl_xor(accr[e], off);
            accn[e] += __shfl_xor(accn[e], off);
        }
    }
    if (lane == 0) {
        float noisy[EE];
#pragma unroll
        for (int e = 0; e < EE; ++e) {
            const float lg = accr[e] + br[e];
            const float nl = accn[e] + bn[e];
            const float sp = fmaxf(nl, 0.f) + log1pf(expf(-fabsf(nl)));  // stable softplus
            noisy[e] = lg + noise[(size_t)t * EE + e] * sp;
        }
        int i0 = 0;
#pragma unroll
        for (int e = 1; e < EE; ++e) if (noisy[e] > noisy[i0]) i0 = e;   // ties -> lowest idx
        int i1 = (i0 == 0) ? 1 : 0;
#pragma unroll
        for (int e = 0; e < EE; ++e) if (e != i0 && noisy[e] > noisy[i1]) i1 = e;
        const float ex = expf(noisy[i1] - noisy[i0]);   // v1 <= v0, ex in (0,1]
        const float g0 = 1.f / (1.f + ex);
        const float g1 = ex / (1.f + ex);

        __half h0 = __float2half_rn(g0), h1 = __float2half_rn(g1);
        const unsigned u0 = (unsigned)t | ((unsigned)*reinterpret_cast<ushort*>(&h0) << 16);
        const unsigned u1 = (unsigned)t | ((unsigned)*reinterpret_cast<ushort*>(&h1) << 16);
        const int ga = i0 * 2 + 0;                      // slot-0 group (top-1)
        const int gb = i1 * 2 + 1;                      // slot-1 group (top-2)
        int p0 = atomicAdd(&cnt[ga], 1);
        entries[ga * NTOK + p0] = u0;
        int p1 = atomicAdd(&cnt[gb], 1);
        entries[gb * NTOK + p1] = u1;
    }
}

// ---------------------------------------------------------------------------
// Kernel 2: fused expert, fp32 I/O, bf16 MFMA internals.
// Per (group, 64-token tile):
//   phase 1: hidden = gelu(x_rows @ Wd[e] + bd[e])  -> LDS bf16 (64 x 512)
//   phase 2: out_rows (+)= (hidden @ Wu[e] + bu[e]) * gate   (fp32 stores)
// s==0 pass: plain store (slot-0 groups cover every token exactly once).
// s==1 pass: read-modify-write add (one writer per element; ordered by the
// kernel boundary between the two launches).
//
// 256 threads = 4 waves; wave w owns token rows [w*16, w*16+16).
// MFMA 16x16x32 bf16. A-frag: A[m=lane&15][k=(lane>>4)*8+j];
// C/D: col=lane&15, row=(lane>>4)*4+reg.
// ---------------------------------------------------------------------------
#define LDH 520
#define LDB 40

__global__ __launch_bounds__(256) void fused_k(
    const float* __restrict__ x,
    const float* __restrict__ Wd, const float* __restrict__ bd,
    const float* __restrict__ Wu, const float* __restrict__ bu,
    const int* __restrict__ cnt, const unsigned* __restrict__ entries,
    float* __restrict__ out, const int s)
{
    const int e = blockIdx.y;
    const int g = e * 2 + s;
    const int n_g = cnt[g];
    const int tm = blockIdx.x;
    if (tm * 64 >= n_g) return;

    __shared__ __align__(16) ushort hid[64 * LDH];
    __shared__ __align__(16) ushort Bst[128 * LDB];
    __shared__ unsigned ecache[64];

    const int tid = threadIdx.x, lane = tid & 63, w = tid >> 6;
    const int fr = lane & 15, fq = lane >> 4;
    const int bk = tid >> 3, bns = tid & 7;   // B staging: k-row 0..31, 8-col segment 0..7

    if (tid < 64) {
        const int ridx = min(tm * 64 + tid, n_g - 1);
        ecache[tid] = entries[g * NTOK + ridx];
    }
    __syncthreads();

    // ---- preload A fragments (this wave's 16 token rows, full K=1024) ----
    const int my_tok = (int)(ecache[w * 16 + fr] & 0xFFFFu);
    const float* xrow = x + (size_t)my_tok * DD;
    short8 areg[32];
#pragma unroll
    for (int kk = 0; kk < 32; ++kk)
        areg[kk] = cvt8(xrow + kk * 32 + fq * 8);

    const float* Wde = Wd + (size_t)e * DD * HH;

    // ---- phase 1: down-GEMM, N-chunks of 128 over H=512 ----
    for (int nc = 0; nc < 4; ++nc) {
        floatx4 acc[8];
#pragma unroll
        for (int i = 0; i < 8; ++i) acc[i] = (floatx4){0.f, 0.f, 0.f, 0.f};
        for (int kk = 0; kk < 32; ++kk) {
            __syncthreads();
            {   // stage B_T[128 n][32 k] from Wd[e][kk*32+k][nc*128+n], cvt fp32->bf16
                const float* src = Wde + (size_t)(kk * 32 + bk) * HH + nc * 128 + bns * 8;
                union { short8 s; ushort h[8]; } b0, b1;
                b0.s = cvt8(src);
                b1.s = cvt8(src + 64);
#pragma unroll
                for (int j = 0; j < 8; ++j) {
                    Bst[(bns * 8 + j) * LDB + bk] = b0.h[j];
                    Bst[(64 + bns * 8 + j) * LDB + bk] = b1.h[j];
                }
            }
            __syncthreads();
#pragma unroll
            for (int nt = 0; nt < 8; ++nt) {
                const short8 bf = *(const short8*)(&Bst[(nt * 16 + fr) * LDB + fq * 8]);
                acc[nt] = __builtin_amdgcn_mfma_f32_16x16x32_bf16(areg[kk], bf, acc[nt], 0, 0, 0);
            }
        }
        // epilogue: +bd, exact gelu, write hidden tile rows (this wave's rows)
#pragma unroll
        for (int nt = 0; nt < 8; ++nt) {
            const int n = nc * 128 + nt * 16 + fr;
            const float bias = bd[e * HH + n];
#pragma unroll
            for (int i = 0; i < 4; ++i) {
                const float v = acc[nt][i] + bias;
                const float ge = 0.5f * v * (1.f + erff(v * 0.7071067811865475f));
                hid[(w * 16 + fq * 4 + i) * LDH + n] = f2bfu(ge);
            }
        }
    }
    __syncthreads();

    // ---- load hidden A-fragments (this wave's own rows; K=512) ----
    short8 hreg[16];
#pragma unroll
    for (int kk = 0; kk < 16; ++kk)
        hreg[kk] = *(const short8*)(&hid[(w * 16 + fr) * LDH + kk * 32 + fq * 8]);

    // token/gate for this lane's C rows (fq*4+i)
    int etok[4]; float egate[4];
#pragma unroll
    for (int i = 0; i < 4; ++i) {
        const unsigned en = ecache[w * 16 + fq * 4 + i];
        etok[i] = (int)(en & 0xFFFFu);
        ushort hb = (ushort)(en >> 16);
        egate[i] = __half2float(*reinterpret_cast<__half*>(&hb));
    }

    const float* Wue = Wu + (size_t)e * HH * DD;

    // ---- phase 2: up-GEMM, N-chunks of 128 over D=1024 ----
    for (int nc = 0; nc < 8; ++nc) {
        floatx4 acc[8];
#pragma unroll
        for (int i = 0; i < 8; ++i) acc[i] = (floatx4){0.f, 0.f, 0.f, 0.f};
        for (int kk = 0; kk < 16; ++kk) {
            __syncthreads();
            {   // stage B_T[128 n][32 k] from Wu[e][kk*32+k][nc*128+n], cvt fp32->bf16
                const float* src = Wue + (size_t)(kk * 32 + bk) * DD + nc * 128 + bns * 8;
                union { short8 s; ushort h[8]; } b0, b1;
                b0.s = cvt8(src);
                b1.s = cvt8(src + 64);
#pragma unroll
                for (int j = 0; j < 8; ++j) {
                    Bst[(bns * 8 + j) * LDB + bk] = b0.h[j];
                    Bst[(64 + bns * 8 + j) * LDB + bk] = b1.h[j];
                }
            }
            __syncthreads();
#pragma unroll
            for (int nt = 0; nt < 8; ++nt) {
                const short8 bf = *(const short8*)(&Bst[(nt * 16 + fr) * LDB + fq * 8]);
                acc[nt] = __builtin_amdgcn_mfma_f32_16x16x32_bf16(hreg[kk], bf, acc[nt], 0, 0, 0);
            }
        }
        // epilogue: +bu, *gate, store (s==0) or add (s==1) into out[token] (fp32)
#pragma unroll
        for (int nt = 0; nt < 8; ++nt) {
            const int n = nc * 128 + nt * 16 + fr;
            const float bias = bu[e * DD + n];
#pragma unroll
            for (int i = 0; i < 4; ++i) {
                const int grow = tm * 64 + w * 16 + fq * 4 + i;
                if (grow < n_g) {
                    const float v = (acc[nt][i] + bias) * egate[i];
                    float* op = out + (size_t)etok[i] * DD + n;
                    if (s == 0) *op = v;
                    else        *op += v;
                }
            }
        }
    }
}

// ---------------------------------------------------------------------------
// Workspace layout (bytes) — total ~1.05 MB:
//   0    cnt     : int  [16]
//   256  entries : u32  [16][16384]   (tok | gate_f16 << 16)   1 MB
// ---------------------------------------------------------------------------
extern "C" void kernel_launch(void* const* d_in, const int* in_sizes, int n_in,
                              void* d_out, int out_size, void* d_ws, size_t ws_size,
                              hipStream_t stream)
{
    const float* x     = (const float*)d_in[0];
    const float* Wr    = (const float*)d_in[1];
    const float* br    = (const float*)d_in[2];
    const float* Wn    = (const float*)d_in[3];
    const float* bn    = (const float*)d_in[4];
    const float* Wd    = (const float*)d_in[5];
    const float* bd    = (const float*)d_in[6];
    const float* Wu    = (const float*)d_in[7];
    const float* bu    = (const float*)d_in[8];
    const float* noise = (const float*)d_in[9];

    char* ws = (char*)d_ws;
    int*      cnt     = (int*)(ws + 0);
    unsigned* entries = (unsigned*)(ws + 256);

    zero_k<<<1, 64, 0, stream>>>(cnt);
    router_k<<<NTOK / 4, 256, 0, stream>>>(x, Wr, br, Wn, bn, noise, cnt, entries);
    fused_k<<<dim3(NTOK / 64, EE), 256, 0, stream>>>(x, Wd, bd, Wu, bu, cnt, entries, (float*)d_out, 0);
    fused_k<<<dim3(NTOK / 64, EE), 256, 0, stream>>>(x, Wd, bd, Wu, bu, cnt, entries, (float*)d_out, 1);
}

// Round 5
// 458.354 us; speedup vs baseline: 4.3490x; 4.3490x over previous
//
#include <hip/hip_runtime.h>
#include <hip/hip_bf16.h>
#include <hip/hip_fp16.h>
#include <math.h>

// Problem constants
#define DD   1024
#define EE   8
#define HH   512
#define NTOK 16384        // B*T
#define NG   16           // (expert, slot) groups
#define MAXMT 24          // max 128-row tiles per group (3072 rows; n_g~2048±45)

typedef __attribute__((ext_vector_type(8))) short short8;   // 8 bf16
typedef __attribute__((ext_vector_type(4))) float floatx4;  // MFMA C/D frag

__device__ __forceinline__ ushort f2bfu(float f) {
    __hip_bfloat16 h = __float2bfloat16(f);   // RNE
    return *reinterpret_cast<ushort*>(&h);
}

// async global->LDS, 16B per lane. LDS dest = wave-uniform base + lane*16.
__device__ __forceinline__ void glds16(const void* g, void* l) {
    __builtin_amdgcn_global_load_lds(
        (const __attribute__((address_space(1))) unsigned int*)g,
        (__attribute__((address_space(3))) unsigned int*)l, 16, 0, 0);
}

// ---------------------------------------------------------------------------
// Kernel 0: zero padded counters (16 ints at 64B stride -> 256 ints)
// ---------------------------------------------------------------------------
__global__ void zero_k(int* __restrict__ cnt) {
    if (blockIdx.x == 0 && threadIdx.x < 256) cnt[threadIdx.x] = 0;
}

// ---------------------------------------------------------------------------
// Kernel 1: cvt x fp32 -> bf16 (8 elems/thread)
// ---------------------------------------------------------------------------
__global__ __launch_bounds__(256) void cvtx_k(const float* __restrict__ x, ushort* __restrict__ xb) {
    const size_t i = ((size_t)blockIdx.x * 256 + threadIdx.x) * 8;
    const float4 a = *(const float4*)(x + i);
    const float4 b = *(const float4*)(x + i + 4);
    ushort o[8];
    o[0]=f2bfu(a.x); o[1]=f2bfu(a.y); o[2]=f2bfu(a.z); o[3]=f2bfu(a.w);
    o[4]=f2bfu(b.x); o[5]=f2bfu(b.y); o[6]=f2bfu(b.z); o[7]=f2bfu(b.w);
    *(uint4*)(xb + i) = *(uint4*)o;
}

// ---------------------------------------------------------------------------
// Kernel 2: per-expert transpose + cvt: src [E][R][C] fp32 -> dst [E][C][R] bf16
// 64x64 tiles, 256 threads, LDS pad 65.
// ---------------------------------------------------------------------------
__global__ __launch_bounds__(256) void trans_k(const float* __restrict__ src, ushort* __restrict__ dst,
                                               const int R, const int C) {
    const int e = blockIdx.z, r0 = blockIdx.y * 64, c0 = blockIdx.x * 64;
    __shared__ float t[64][65];
    const int tid = threadIdx.x;
    const int cseg = (tid & 15) * 4, rr = tid >> 4;          // rr 0..15
#pragma unroll
    for (int j = 0; j < 4; ++j) {
        const int r = rr + j * 16;
        const float4 v = *(const float4*)(src + ((size_t)e * R + r0 + r) * C + c0 + cseg);
        t[r][cseg] = v.x; t[r][cseg+1] = v.y; t[r][cseg+2] = v.z; t[r][cseg+3] = v.w;
    }
    __syncthreads();
    const int rseg = (tid & 15) * 4;
#pragma unroll
    for (int j = 0; j < 4; ++j) {
        const int crow = (tid >> 4) + j * 16;
        ushort o[4];
#pragma unroll
        for (int q = 0; q < 4; ++q) o[q] = f2bfu(t[rseg + q][crow]);
        *(uint2*)(dst + ((size_t)e * C + c0 + crow) * R + r0 + rseg) = *(uint2*)o;
    }
}

// ---------------------------------------------------------------------------
// Kernel 3: router (fp32). One wave/token; padded counters (stride 16 ints).
// entry = tok | gate_f16 << 16, appended to group g = expert*2 + slot.
// ---------------------------------------------------------------------------
__global__ __launch_bounds__(256) void router_k(
    const float* __restrict__ x, const float* __restrict__ Wr, const float* __restrict__ br,
    const float* __restrict__ Wn, const float* __restrict__ bn, const float* __restrict__ noise,
    int* __restrict__ cnt, unsigned* __restrict__ entries)
{
    const int wave = threadIdx.x >> 6;
    const int lane = threadIdx.x & 63;
    const int t = blockIdx.x * 4 + wave;

    float accr[EE], accn[EE];
#pragma unroll
    for (int e = 0; e < EE; ++e) { accr[e] = 0.f; accn[e] = 0.f; }

    const float* xr = x + (size_t)t * DD;
#pragma unroll 4
    for (int it = 0; it < DD / 64; ++it) {
        const int d = it * 64 + lane;
        const float xv = xr[d];
        float wr[8], wn[8];
        *(float4*)&wr[0] = *(const float4*)(Wr + (size_t)d * EE);
        *(float4*)&wr[4] = *(const float4*)(Wr + (size_t)d * EE + 4);
        *(float4*)&wn[0] = *(const float4*)(Wn + (size_t)d * EE);
        *(float4*)&wn[4] = *(const float4*)(Wn + (size_t)d * EE + 4);
#pragma unroll
        for (int e = 0; e < EE; ++e) {
            accr[e] = fmaf(xv, wr[e], accr[e]);
            accn[e] = fmaf(xv, wn[e], accn[e]);
        }
    }
#pragma unroll
    for (int off = 32; off > 0; off >>= 1) {
#pragma unroll
        for (int e = 0; e < EE; ++e) {
            accr[e] += __shfl_xor(accr[e], off);
            accn[e] += __shfl_xor(accn[e], off);
        }
    }
    if (lane == 0) {
        float noisy[EE];
#pragma unroll
        for (int e = 0; e < EE; ++e) {
            const float lg = accr[e] + br[e];
            const float nl = accn[e] + bn[e];
            const float sp = fmaxf(nl, 0.f) + log1pf(expf(-fabsf(nl)));
            noisy[e] = lg + noise[(size_t)t * EE + e] * sp;
        }
        int i0 = 0;
#pragma unroll
        for (int e = 1; e < EE; ++e) if (noisy[e] > noisy[i0]) i0 = e;
        int i1 = (i0 == 0) ? 1 : 0;
#pragma unroll
        for (int e = 0; e < EE; ++e) if (e != i0 && noisy[e] > noisy[i1]) i1 = e;
        const float ex = expf(noisy[i1] - noisy[i0]);
        const float g0 = 1.f / (1.f + ex);
        const float g1 = ex / (1.f + ex);
        __half h0 = __float2half_rn(g0), h1 = __float2half_rn(g1);
        const unsigned u0 = (unsigned)t | ((unsigned)*reinterpret_cast<ushort*>(&h0) << 16);
        const unsigned u1 = (unsigned)t | ((unsigned)*reinterpret_cast<ushort*>(&h1) << 16);
        const int ga = i0 * 2 + 0, gb = i1 * 2 + 1;
        int p0 = atomicAdd(&cnt[ga * 16], 1);
        entries[ga * NTOK + p0] = u0;
        int p1 = atomicAdd(&cnt[gb * 16], 1);
        entries[gb * NTOK + p1] = u1;
    }
}

// Kernel 4: exclusive prefix over 16 group counts
__global__ void offsets_k(const int* __restrict__ cnt, int* __restrict__ off) {
    if (threadIdx.x == 0 && blockIdx.x == 0) {
        int s = 0;
        for (int g = 0; g < NG; ++g) { off[g] = s; s += cnt[g * 16]; }
    }
}

// ---------------------------------------------------------------------------
// Grouped GEMM, m97 structure: 128x128x32 tile, 256 threads = 4 waves (2x2),
// each wave 64x64 via 4x4 MFMA 16x16x32 frags. A,B tiles 128x32 bf16,
// lane-linear (global_load_lds width 16). 2-barrier K-loop.
// A-frag A[m=lane&15][k=(lane>>4)*8+j]; C/D col=lane&15, row=(lane>>4)*4+reg.
// ---------------------------------------------------------------------------

// Kernel 5: down: hidden[off+row][n] = gelu(x_gathered @ WdT^T + bd)
__global__ __launch_bounds__(256) void down_k(
    const ushort* __restrict__ xb, const ushort* __restrict__ WdT, const float* __restrict__ bd,
    const int* __restrict__ cnt, const int* __restrict__ off,
    const unsigned* __restrict__ entries, ushort* __restrict__ hid)
{
    const int g = blockIdx.z, e = g >> 1;
    const int n_g = cnt[g * 16];
    const int tm = blockIdx.y;
    if (tm * 128 >= n_g) return;
    const int n0 = blockIdx.x * 128;

    __shared__ __align__(16) ushort As[128 * 32];
    __shared__ __align__(16) ushort Bs[128 * 32];
    __shared__ unsigned ecache[128];

    const int tid = threadIdx.x, lane = tid & 63, w = tid >> 6;
    const int wm = w >> 1, wn = w & 1;
    const int fr = lane & 15, fq = lane >> 4;

    if (tid < 128) {
        const int ridx = min(tm * 128 + tid, n_g - 1);
        ecache[tid] = entries[g * NTOK + ridx];
    }
    __syncthreads();

    // staging geometry: flat unit = r*256 + w*64 + lane; row = flat>>2, seg = flat&3
    const int u0 = w * 64 + lane;
    const int rowA0 = u0 >> 2, rowA1 = rowA0 + 64, seg = u0 & 3;
    const ushort* gA0 = xb + (size_t)(ecache[rowA0] & 0xFFFFu) * DD + seg * 8;
    const ushort* gA1 = xb + (size_t)(ecache[rowA1] & 0xFFFFu) * DD + seg * 8;
    const ushort* WTe = WdT + (size_t)e * HH * DD;
    const ushort* gB0 = WTe + (size_t)(n0 + rowA0) * DD + seg * 8;
    const ushort* gB1 = WTe + (size_t)(n0 + rowA1) * DD + seg * 8;
    char* lA0 = (char*)As + (size_t)(w * 64) * 16;
    char* lA1 = (char*)As + (size_t)(256 + w * 64) * 16;
    char* lB0 = (char*)Bs + (size_t)(w * 64) * 16;
    char* lB1 = (char*)Bs + (size_t)(256 + w * 64) * 16;

    floatx4 acc[4][4];
#pragma unroll
    for (int i = 0; i < 4; ++i)
#pragma unroll
        for (int j = 0; j < 4; ++j) acc[i][j] = (floatx4){0.f, 0.f, 0.f, 0.f};

    for (int k0 = 0; k0 < DD; k0 += 32) {
        __syncthreads();
        glds16(gA0 + k0, lA0);
        glds16(gA1 + k0, lA1);
        glds16(gB0 + k0, lB0);
        glds16(gB1 + k0, lB1);
        __syncthreads();
        short8 a[4], b[4];
#pragma unroll
        for (int mt = 0; mt < 4; ++mt)
            a[mt] = *(const short8*)&As[(wm * 64 + mt * 16 + fr) * 32 + fq * 8];
#pragma unroll
        for (int nt = 0; nt < 4; ++nt)
            b[nt] = *(const short8*)&Bs[(wn * 64 + nt * 16 + fr) * 32 + fq * 8];
#pragma unroll
        for (int mt = 0; mt < 4; ++mt)
#pragma unroll
            for (int nt = 0; nt < 4; ++nt)
                acc[mt][nt] = __builtin_amdgcn_mfma_f32_16x16x32_bf16(a[mt], b[nt], acc[mt][nt], 0, 0, 0);
    }

    const int hbase = off[g] + tm * 128;
#pragma unroll
    for (int nt = 0; nt < 4; ++nt) {
        const int n = n0 + wn * 64 + nt * 16 + fr;
        const float bias = bd[e * HH + n];
#pragma unroll
        for (int mt = 0; mt < 4; ++mt)
#pragma unroll
            for (int i = 0; i < 4; ++i) {
                const int rl = wm * 64 + mt * 16 + fq * 4 + i;
                if (tm * 128 + rl < n_g) {
                    const float v = acc[mt][nt][i] + bias;
                    const float ge = 0.5f * v * (1.f + erff(v * 0.7071067811865475f));
                    hid[(size_t)(hbase + rl) * HH + n] = f2bfu(ge);
                }
            }
    }
}

// Kernel 6: up: out[tok][n] (s=0: =, s=1: +=) (hidden @ WuT^T + bu) * gate
__global__ __launch_bounds__(256) void up_k(
    const ushort* __restrict__ hid, const ushort* __restrict__ WuT, const float* __restrict__ bu,
    const int* __restrict__ cnt, const int* __restrict__ off,
    const unsigned* __restrict__ entries, float* __restrict__ out, const int s)
{
    const int e = blockIdx.z, g = e * 2 + s;
    const int n_g = cnt[g * 16];
    const int tm = blockIdx.y;
    if (tm * 128 >= n_g) return;
    const int n0 = blockIdx.x * 128;

    __shared__ __align__(16) ushort As[128 * 32];
    __shared__ __align__(16) ushort Bs[128 * 32];
    __shared__ unsigned ecache[128];

    const int tid = threadIdx.x, lane = tid & 63, w = tid >> 6;
    const int wm = w >> 1, wn = w & 1;
    const int fr = lane & 15, fq = lane >> 4;

    if (tid < 128) {
        const int ridx = min(tm * 128 + tid, n_g - 1);
        ecache[tid] = entries[g * NTOK + ridx];
    }
    __syncthreads();

    const int u0 = w * 64 + lane;
    const int rowA0 = u0 >> 2, rowA1 = rowA0 + 64, seg = u0 & 3;
    const int ar0 = min(tm * 128 + rowA0, n_g - 1);
    const int ar1 = min(tm * 128 + rowA1, n_g - 1);
    const ushort* gA0 = hid + (size_t)(off[g] + ar0) * HH + seg * 8;
    const ushort* gA1 = hid + (size_t)(off[g] + ar1) * HH + seg * 8;
    const ushort* WTe = WuT + (size_t)e * DD * HH;
    const ushort* gB0 = WTe + (size_t)(n0 + rowA0) * HH + seg * 8;
    const ushort* gB1 = WTe + (size_t)(n0 + rowA1) * HH + seg * 8;
    char* lA0 = (char*)As + (size_t)(w * 64) * 16;
    char* lA1 = (char*)As + (size_t)(256 + w * 64) * 16;
    char* lB0 = (char*)Bs + (size_t)(w * 64) * 16;
    char* lB1 = (char*)Bs + (size_t)(256 + w * 64) * 16;

    floatx4 acc[4][4];
#pragma unroll
    for (int i = 0; i < 4; ++i)
#pragma unroll
        for (int j = 0; j < 4; ++j) acc[i][j] = (floatx4){0.f, 0.f, 0.f, 0.f};

    for (int k0 = 0; k0 < HH; k0 += 32) {
        __syncthreads();
        glds16(gA0 + k0, lA0);
        glds16(gA1 + k0, lA1);
        glds16(gB0 + k0, lB0);
        glds16(gB1 + k0, lB1);
        __syncthreads();
        short8 a[4], b[4];
#pragma unroll
        for (int mt = 0; mt < 4; ++mt)
            a[mt] = *(const short8*)&As[(wm * 64 + mt * 16 + fr) * 32 + fq * 8];
#pragma unroll
        for (int nt = 0; nt < 4; ++nt)
            b[nt] = *(const short8*)&Bs[(wn * 64 + nt * 16 + fr) * 32 + fq * 8];
#pragma unroll
        for (int mt = 0; mt < 4; ++mt)
#pragma unroll
            for (int nt = 0; nt < 4; ++nt)
                acc[mt][nt] = __builtin_amdgcn_mfma_f32_16x16x32_bf16(a[mt], b[nt], acc[mt][nt], 0, 0, 0);
    }

#pragma unroll
    for (int nt = 0; nt < 4; ++nt) {
        const int n = n0 + wn * 64 + nt * 16 + fr;
        const float bias = bu[e * DD + n];
#pragma unroll
        for (int mt = 0; mt < 4; ++mt)
#pragma unroll
            for (int i = 0; i < 4; ++i) {
                const int rl = wm * 64 + mt * 16 + fq * 4 + i;
                if (tm * 128 + rl < n_g) {
                    const unsigned en = ecache[rl];
                    const int tok = (int)(en & 0xFFFFu);
                    ushort hb = (ushort)(en >> 16);
                    const float gate = __half2float(*reinterpret_cast<__half*>(&hb));
                    const float v = (acc[mt][nt][i] + bias) * gate;
                    float* op = out + (size_t)tok * DD + n;
                    if (s == 0) *op = v;
                    else        *op += v;
                }
            }
    }
}

// ---------------------------------------------------------------------------
// Workspace layout (bytes), total ~81 MB:
//   0         cnt    : int[16] @ 64B stride (1 KB)
//   1024      off    : int[16] (pad to 1 KB)
//   2048      entries: u32[16][16384]            (1 MB)
//   1050624   xb     : bf16 [16384][1024]        (32 MB)
//   34605056  WdT    : bf16 [8][512 h][1024 d]   (8 MB)
//   42993664  WuT    : bf16 [8][1024 d][512 h]   (8 MB)
//   51382272  hid    : bf16 [32768][512]         (32 MB)
// ---------------------------------------------------------------------------
extern "C" void kernel_launch(void* const* d_in, const int* in_sizes, int n_in,
                              void* d_out, int out_size, void* d_ws, size_t ws_size,
                              hipStream_t stream)
{
    const float* x     = (const float*)d_in[0];
    const float* Wr    = (const float*)d_in[1];
    const float* br    = (const float*)d_in[2];
    const float* Wn    = (const float*)d_in[3];
    const float* bn    = (const float*)d_in[4];
    const float* Wd    = (const float*)d_in[5];
    const float* bd    = (const float*)d_in[6];
    const float* Wu    = (const float*)d_in[7];
    const float* bu    = (const float*)d_in[8];
    const float* noise = (const float*)d_in[9];

    char* ws = (char*)d_ws;
    int*      cnt     = (int*)(ws + 0);
    int*      off     = (int*)(ws + 1024);
    unsigned* entries = (unsigned*)(ws + 2048);
    ushort*   xb      = (ushort*)(ws + 1050624);
    ushort*   WdT     = (ushort*)(ws + 34605056);
    ushort*   WuT     = (ushort*)(ws + 42993664);
    ushort*   hid     = (ushort*)(ws + 51382272);

    zero_k<<<1, 256, 0, stream>>>(cnt);
    cvtx_k<<<(NTOK * DD) / (256 * 8), 256, 0, stream>>>(x, xb);
    trans_k<<<dim3(HH / 64, DD / 64, EE), 256, 0, stream>>>(Wd, WdT, DD, HH);  // [d][h]->[h][d]
    trans_k<<<dim3(DD / 64, HH / 64, EE), 256, 0, stream>>>(Wu, WuT, HH, DD);  // [h][d]->[d][h]
    router_k<<<NTOK / 4, 256, 0, stream>>>(x, Wr, br, Wn, bn, noise, cnt, entries);
    offsets_k<<<1, 64, 0, stream>>>(cnt, off);
    down_k<<<dim3(HH / 128, MAXMT, NG), 256, 0, stream>>>(xb, WdT, bd, cnt, off, entries, hid);
    up_k<<<dim3(DD / 128, MAXMT, EE), 256, 0, stream>>>(hid, WuT, bu, cnt, off, entries, (float*)d_out, 0);
    up_k<<<dim3(DD / 128, MAXMT, EE), 256, 0, stream>>>(hid, WuT, bu, cnt, off, entries, (float*)d_out, 1);
}